// Round 2
// baseline (839.792 us; speedup 1.0000x reference)
//
#include <hip/hip_runtime.h>

// HolographicLayer score: eta = r2v . ccorr_half(s2v, o2v)
//   c[k] = sum_i s2v[k+i-100] * o2v[i]   (zero-padded cross-correlation, d=201)
//   eta  = sum_k r2v[k] * c[k]
// Only x[0,:] is used: s=x[0], o=x[1], p=x[2].
// All tensors are fp32 (reference dtype); output is one fp32 scalar.
// ~40k FMAs + ~2.4 KB HBM -> single tiny workgroup; launch-latency bound.

__global__ __launch_bounds__(256) void holo_score_kernel(
    const int* __restrict__ x,
    const float* __restrict__ E,
    const float* __restrict__ R,
    float* __restrict__ out)
{
    constexpr int D   = 201;
    constexpr int PAD = 100;

    __shared__ float spad[D + 2 * PAD];  // s2v with 100 zeros each side (401 floats)
    __shared__ float ov[D];
    __shared__ float rv[D];
    __shared__ float wsum[4];            // one partial per 64-lane wave

    const int tid = threadIdx.x;
    const long long s = x[0];
    const long long o = x[1];
    const long long p = x[2];

    // zero the padded s-buffer, then fill the center
    for (int j = tid; j < D + 2 * PAD; j += 256) spad[j] = 0.0f;
    __syncthreads();
    if (tid < D) {
        spad[PAD + tid] = E[s * D + tid];
        ov[tid]         = E[o * D + tid];
        rv[tid]         = R[p * D + tid];
    }
    __syncthreads();

    // thread k: partial = r[k] * sum_i spad[k+i] * ov[i]
    // stride-1 LDS reads: 64 lanes over 32 banks = 2-way aliasing (free);
    // ov[i] is a same-address broadcast (free).
    float partial = 0.0f;
    if (tid < D) {
        float c = 0.0f;
        #pragma unroll 8
        for (int i = 0; i < D; ++i)
            c = fmaf(spad[tid + i], ov[i], c);
        partial = rv[tid] * c;
    }

    // 64-lane wave reduction (wave = 64 on CDNA)
    for (int off = 32; off > 0; off >>= 1)
        partial += __shfl_down(partial, off, 64);
    if ((tid & 63) == 0) wsum[tid >> 6] = partial;
    __syncthreads();

    if (tid == 0) {
        out[0] = wsum[0] + wsum[1] + wsum[2] + wsum[3];
    }
}

extern "C" void kernel_launch(void* const* d_in, const int* in_sizes, int n_in,
                              void* d_out, int out_size, void* d_ws, size_t ws_size,
                              hipStream_t stream) {
    const int*   x   = (const int*)d_in[0];
    const float* E   = (const float*)d_in[1];
    const float* R   = (const float*)d_in[2];
    float*       out = (float*)d_out;

    hipLaunchKernelGGL(holo_score_kernel, dim3(1), dim3(256), 0, stream,
                       x, E, R, out);
}